// Round 2
// baseline (259.901 us; speedup 1.0000x reference)
//
#include <hip/hip_runtime.h>
#include <hip/hip_bf16.h>

#define B_ 4
#define T_ 4096
#define C_ 1024
#define H_ 128

typedef __attribute__((ext_vector_type(8))) short short8;
typedef __attribute__((ext_vector_type(4))) float f32x4;
typedef __attribute__((ext_vector_type(4))) unsigned short u16x4;

static __device__ __forceinline__ unsigned short f2bf(float f) {
    union { float f; unsigned u; } v; v.f = f;
    unsigned r = v.u + 0x7FFF + ((v.u >> 16) & 1);
    return (unsigned short)(r >> 16);
}

// ---------------- W transpose: [C][H] fp32 -> [H][C] bf16 ----------------
__global__ void wt_kernel(const float* __restrict__ Wq, const float* __restrict__ Wk,
                          const float* __restrict__ Wv, unsigned short* __restrict__ Wt) {
    __shared__ float tile[64][65];
    int c0 = blockIdx.x * 64, h0 = blockIdx.y * 64, w = blockIdx.z;
    const float* W = (w == 0) ? Wq : (w == 1) ? Wk : Wv;
    unsigned short* dst = Wt + (size_t)w * H_ * C_;
    int tr = threadIdx.x >> 6, tc = threadIdx.x & 63;
#pragma unroll
    for (int p = 0; p < 16; ++p) {
        int r = p * 4 + tr;
        tile[r][tc] = W[(size_t)(c0 + r) * H_ + h0 + tc];
    }
    __syncthreads();
#pragma unroll
    for (int p = 0; p < 16; ++p) {
        int r = p * 4 + tr; // h index
        dst[(size_t)(h0 + r) * C_ + c0 + tc] = f2bf(tile[tc][r]);
    }
}

// ---------------- QKV projection GEMM: [16384 x 1024] * [1024 x 128] ----------------
// grid (M/128, 3). w=0 -> Q row-major, w=1 -> K row-major, w=2 -> V transposed [B][H][T]
__global__ __launch_bounds__(256) void proj_kernel(
        const float* __restrict__ x, const unsigned short* __restrict__ Wt3,
        unsigned short* __restrict__ Q, unsigned short* __restrict__ K,
        unsigned short* __restrict__ Vt) {
    __shared__ unsigned short Xs[128][72];
    __shared__ unsigned short Ws[128][72];
    int m0 = blockIdx.x * 128;
    int w = blockIdx.y;
    const unsigned short* Wt = Wt3 + (size_t)w * H_ * C_;
    int tid = threadIdx.x;
    int lane = tid & 63, wid = tid >> 6;
    int wr = wid >> 1, wc = wid & 1;
    int l15 = lane & 15, g = lane >> 4;

    f32x4 acc[4][4];
#pragma unroll
    for (int i = 0; i < 4; i++)
#pragma unroll
        for (int j = 0; j < 4; j++) acc[i][j] = (f32x4)0.0f;

    for (int kt = 0; kt < C_ / 64; ++kt) {
        int k0 = kt * 64;
        // stage X tile [128][64] fp32 -> bf16 (2048 float4 chunks / 256 thr = 8 each)
#pragma unroll
        for (int p = 0; p < 8; ++p) {
            int idx = tid + p * 256;
            int r = idx >> 4, c = (idx & 15) * 4;
            float4 v = *(const float4*)(x + (size_t)(m0 + r) * C_ + k0 + c);
            u16x4 o;
            o.x = f2bf(v.x); o.y = f2bf(v.y); o.z = f2bf(v.z); o.w = f2bf(v.w);
            *(u16x4*)&Xs[r][c] = o;
        }
        // stage Wt tile [128][64] bf16 (1024 short8 chunks / 256 thr = 4 each)
#pragma unroll
        for (int p = 0; p < 4; ++p) {
            int idx = tid + p * 256;
            int r = idx >> 3, c = (idx & 7) * 8;
            *(short8*)&Ws[r][c] = *(const short8*)(Wt + (size_t)r * C_ + k0 + c);
        }
        __syncthreads();
#pragma unroll
        for (int kf = 0; kf < 2; ++kf) {
            short8 a[4], bvec[4];
#pragma unroll
            for (int mt = 0; mt < 4; mt++) a[mt] = *(const short8*)&Xs[wr * 64 + mt * 16 + l15][kf * 32 + g * 8];
#pragma unroll
            for (int nt = 0; nt < 4; nt++) bvec[nt] = *(const short8*)&Ws[wc * 64 + nt * 16 + l15][kf * 32 + g * 8];
#pragma unroll
            for (int mt = 0; mt < 4; mt++)
#pragma unroll
                for (int nt = 0; nt < 4; nt++)
                    acc[mt][nt] = __builtin_amdgcn_mfma_f32_16x16x32_bf16(a[mt], bvec[nt], acc[mt][nt], 0, 0, 0);
        }
        __syncthreads();
    }
    // epilogue: C/D layout col=lane&15, row=(lane>>4)*4+ri
    if (w < 2) {
        unsigned short* outp = (w == 0) ? Q : K;
#pragma unroll
        for (int mt = 0; mt < 4; mt++)
#pragma unroll
            for (int nt = 0; nt < 4; nt++) {
                int row0 = m0 + wr * 64 + mt * 16 + g * 4;
                int col = wc * 64 + nt * 16 + l15;
#pragma unroll
                for (int ri = 0; ri < 4; ri++)
                    outp[(size_t)(row0 + ri) * H_ + col] = f2bf(acc[mt][nt][ri]);
            }
    } else {
        int b = m0 / T_;          // 32 blocks per batch, no straddling
        int tbase = m0 - b * T_;
#pragma unroll
        for (int mt = 0; mt < 4; mt++)
#pragma unroll
            for (int nt = 0; nt < 4; nt++) {
                int t0 = tbase + wr * 64 + mt * 16 + g * 4;
                int col = wc * 64 + nt * 16 + l15;
                u16x4 o;
                o.x = f2bf(acc[mt][nt][0]); o.y = f2bf(acc[mt][nt][1]);
                o.z = f2bf(acc[mt][nt][2]); o.w = f2bf(acc[mt][nt][3]);
                *(u16x4*)&Vt[(size_t)(b * H_ + col) * T_ + t0] = o;
            }
    }
}

// ---------------- Flash attention: QBLK=64 (4 waves x 16 rows), KBLK=64 ----------------
__global__ __launch_bounds__(256) void attn_kernel(
        const unsigned short* __restrict__ Q, const unsigned short* __restrict__ K,
        const unsigned short* __restrict__ Vt, float* __restrict__ out) {
    __shared__ unsigned short Ks[64][136];   // +8 pad: 272B row stride, 16B aligned
    __shared__ unsigned short Vs[128][72];   // V^T tile [h][t], +8 pad
    __shared__ unsigned short Ps[4][16][72]; // per-wave P tile [q][kk], +8 pad
    int qb = blockIdx.x, b = blockIdx.y;
    int tid = threadIdx.x, lane = tid & 63, wid = tid >> 6;
    int l15 = lane & 15, g = lane >> 4;
    int q0w = qb * 64 + wid * 16;
    const float alpha = 0.08838834764831845f; // 1/sqrt(128)

    // Q fragments held in registers for the whole block
    short8 aq[4];
#pragma unroll
    for (int kf = 0; kf < 4; kf++)
        aq[kf] = *(const short8*)(Q + (size_t)(b * T_ + q0w + l15) * H_ + kf * 32 + g * 8);

    f32x4 o[8];
#pragma unroll
    for (int i = 0; i < 8; i++) o[i] = (f32x4)0.0f;
    float m_run[4], l_run[4];
#pragma unroll
    for (int ri = 0; ri < 4; ri++) { m_run[ri] = -1e30f; l_run[ri] = 0.f; }

    for (int kt = 0; kt <= qb; ++kt) {
        int k0 = kt * 64;
        // stage K tile [64][128]
#pragma unroll
        for (int p = 0; p < 4; ++p) {
            int idx = tid + p * 256;
            int r = idx >> 4, c = (idx & 15) * 8;
            *(short8*)&Ks[r][c] = *(const short8*)(K + (size_t)(b * T_ + k0 + r) * H_ + c);
        }
        // stage V^T tile [128][64]
#pragma unroll
        for (int p = 0; p < 4; ++p) {
            int idx = tid + p * 256;
            int r = idx >> 3, c = (idx & 7) * 8;
            *(short8*)&Vs[r][c] = *(const short8*)(Vt + (size_t)(b * H_ + r) * T_ + k0 + c);
        }
        __syncthreads();

        // S = Q K^T  (16 q-rows x 64 kk), fp32 accum
        f32x4 s[4];
#pragma unroll
        for (int ct = 0; ct < 4; ct++) {
            s[ct] = (f32x4)0.0f;
#pragma unroll
            for (int kf = 0; kf < 4; kf++) {
                short8 bk = *(const short8*)&Ks[ct * 16 + l15][kf * 32 + g * 8];
                s[ct] = __builtin_amdgcn_mfma_f32_16x16x32_bf16(aq[kf], bk, s[ct], 0, 0, 0);
            }
        }
        bool diag = (kt == qb);
#pragma unroll
        for (int ct = 0; ct < 4; ct++)
#pragma unroll
            for (int ri = 0; ri < 4; ri++) {
                float v = s[ct][ri] * alpha;
                if (diag) {
                    int kkg = k0 + ct * 16 + l15;
                    int qg = q0w + g * 4 + ri;
                    if (kkg > qg) v = -1e30f;
                }
                s[ct][ri] = v;
            }

        // online softmax (row = 4g+ri, cols spread over 16 lanes x 4 ct)
        float pbuf[4][4];
#pragma unroll
        for (int ri = 0; ri < 4; ri++) {
            float mx = fmaxf(fmaxf(s[0][ri], s[1][ri]), fmaxf(s[2][ri], s[3][ri]));
#pragma unroll
            for (int off = 1; off < 16; off <<= 1)
                mx = fmaxf(mx, __shfl_xor(mx, off, 64));
            float m_new = fmaxf(m_run[ri], mx);
            float resc = __expf(m_run[ri] - m_new);
            float sum = 0.f;
#pragma unroll
            for (int ct = 0; ct < 4; ct++) {
                float p = __expf(s[ct][ri] - m_new);
                pbuf[ct][ri] = p;
                sum += p;
            }
#pragma unroll
            for (int off = 1; off < 16; off <<= 1)
                sum += __shfl_xor(sum, off, 64);
            l_run[ri] = l_run[ri] * resc + sum;
            m_run[ri] = m_new;
#pragma unroll
            for (int i = 0; i < 8; i++) o[i][ri] *= resc;
        }
        // P acc-layout -> LDS (per-wave, no barrier needed)
#pragma unroll
        for (int ct = 0; ct < 4; ct++)
#pragma unroll
            for (int ri = 0; ri < 4; ri++)
                Ps[wid][g * 4 + ri][ct * 16 + l15] = f2bf(pbuf[ct][ri]);

        // O += P V
#pragma unroll
        for (int kf2 = 0; kf2 < 2; kf2++) {
            short8 ap = *(const short8*)&Ps[wid][l15][kf2 * 32 + g * 8];
#pragma unroll
            for (int ht = 0; ht < 8; ht++) {
                short8 bv = *(const short8*)&Vs[ht * 16 + l15][kf2 * 32 + g * 8];
                o[ht] = __builtin_amdgcn_mfma_f32_16x16x32_bf16(ap, bv, o[ht], 0, 0, 0);
            }
        }
        __syncthreads();
    }

    // epilogue: normalize, fp32 out
#pragma unroll
    for (int ri = 0; ri < 4; ri++) {
        float inv = 1.0f / l_run[ri];
        int qg = q0w + g * 4 + ri;
#pragma unroll
        for (int ht = 0; ht < 8; ht++)
            out[(size_t)(b * T_ + qg) * H_ + ht * 16 + l15] = o[ht][ri] * inv;
    }
}

extern "C" void kernel_launch(void* const* d_in, const int* in_sizes, int n_in,
                              void* d_out, int out_size, void* d_ws, size_t ws_size,
                              hipStream_t stream) {
    const float* x  = (const float*)d_in[0];
    const float* Wq = (const float*)d_in[1];
    const float* Wk = (const float*)d_in[2];
    const float* Wv = (const float*)d_in[3];
    float* out = (float*)d_out;

    unsigned short* Wt = (unsigned short*)d_ws;              // [3][H][C] bf16
    unsigned short* Qb = Wt + 3 * (size_t)H_ * C_;           // [B][T][H] bf16
    unsigned short* Kb = Qb + (size_t)B_ * T_ * H_;          // [B][T][H] bf16
    unsigned short* Vt = Kb + (size_t)B_ * T_ * H_;          // [B][H][T] bf16

    wt_kernel<<<dim3(C_ / 64, H_ / 64, 3), 256, 0, stream>>>(Wq, Wk, Wv, Wt);
    proj_kernel<<<dim3((B_ * T_) / 128, 3), 256, 0, stream>>>(x, Wt, Qb, Kb, Vt);
    attn_kernel<<<dim3(T_ / 64, B_), 256, 0, stream>>>(Qb, Kb, Vt, out);
}

// Round 3
// 205.884 us; speedup vs baseline: 1.2624x; 1.2624x over previous
//
#include <hip/hip_runtime.h>
#include <hip/hip_bf16.h>

#define B_ 4
#define T_ 4096
#define C_ 1024
#define H_ 128
#define SEG_ 16   // K-tiles per segment (16*64=1024 keys)

typedef __attribute__((ext_vector_type(8))) short short8;
typedef __attribute__((ext_vector_type(4))) float f32x4;
typedef __attribute__((ext_vector_type(4))) unsigned short u16x4;

static __device__ __forceinline__ unsigned short f2bf(float f) {
    union { float f; unsigned u; } v; v.f = f;
    unsigned r = v.u + 0x7FFF + ((v.u >> 16) & 1);
    return (unsigned short)(r >> 16);
}

// ---------------- W transpose: [C][H] fp32 -> [H][C] bf16 ----------------
__global__ void wt_kernel(const float* __restrict__ Wq, const float* __restrict__ Wk,
                          const float* __restrict__ Wv, unsigned short* __restrict__ Wt) {
    __shared__ float tile[64][65];
    int c0 = blockIdx.x * 64, h0 = blockIdx.y * 64, w = blockIdx.z;
    const float* W = (w == 0) ? Wq : (w == 1) ? Wk : Wv;
    unsigned short* dst = Wt + (size_t)w * H_ * C_;
    int tr = threadIdx.x >> 6, tc = threadIdx.x & 63;
#pragma unroll
    for (int p = 0; p < 16; ++p) {
        int r = p * 4 + tr;
        tile[r][tc] = W[(size_t)(c0 + r) * H_ + h0 + tc];
    }
    __syncthreads();
#pragma unroll
    for (int p = 0; p < 16; ++p) {
        int r = p * 4 + tr; // h index
        dst[(size_t)(h0 + r) * C_ + c0 + tc] = f2bf(tile[tc][r]);
    }
}

// ---------------- QKV projection GEMM: [16384 x 1024] * [1024 x 128] ----------------
// grid (M/128, 3). w=0 -> Q row-major, w=1 -> K row-major, w=2 -> V transposed [B][H][T]
__global__ __launch_bounds__(256) void proj_kernel(
        const float* __restrict__ x, const unsigned short* __restrict__ Wt3,
        unsigned short* __restrict__ Q, unsigned short* __restrict__ K,
        unsigned short* __restrict__ Vt) {
    __shared__ unsigned short Xs[128][72];
    __shared__ unsigned short Ws[128][72];
    int m0 = blockIdx.x * 128;
    int w = blockIdx.y;
    const unsigned short* Wt = Wt3 + (size_t)w * H_ * C_;
    int tid = threadIdx.x;
    int lane = tid & 63, wid = tid >> 6;
    int wr = wid >> 1, wc = wid & 1;
    int l15 = lane & 15, g = lane >> 4;

    f32x4 acc[4][4];
#pragma unroll
    for (int i = 0; i < 4; i++)
#pragma unroll
        for (int j = 0; j < 4; j++) acc[i][j] = (f32x4)0.0f;

    for (int kt = 0; kt < C_ / 64; ++kt) {
        int k0 = kt * 64;
#pragma unroll
        for (int p = 0; p < 8; ++p) {
            int idx = tid + p * 256;
            int r = idx >> 4, c = (idx & 15) * 4;
            float4 v = *(const float4*)(x + (size_t)(m0 + r) * C_ + k0 + c);
            u16x4 o;
            o.x = f2bf(v.x); o.y = f2bf(v.y); o.z = f2bf(v.z); o.w = f2bf(v.w);
            *(u16x4*)&Xs[r][c] = o;
        }
#pragma unroll
        for (int p = 0; p < 4; ++p) {
            int idx = tid + p * 256;
            int r = idx >> 3, c = (idx & 7) * 8;
            *(short8*)&Ws[r][c] = *(const short8*)(Wt + (size_t)r * C_ + k0 + c);
        }
        __syncthreads();
#pragma unroll
        for (int kf = 0; kf < 2; ++kf) {
            short8 a[4], bvec[4];
#pragma unroll
            for (int mt = 0; mt < 4; mt++) a[mt] = *(const short8*)&Xs[wr * 64 + mt * 16 + l15][kf * 32 + g * 8];
#pragma unroll
            for (int nt = 0; nt < 4; nt++) bvec[nt] = *(const short8*)&Ws[wc * 64 + nt * 16 + l15][kf * 32 + g * 8];
#pragma unroll
            for (int mt = 0; mt < 4; mt++)
#pragma unroll
                for (int nt = 0; nt < 4; nt++)
                    acc[mt][nt] = __builtin_amdgcn_mfma_f32_16x16x32_bf16(a[mt], bvec[nt], acc[mt][nt], 0, 0, 0);
        }
        __syncthreads();
    }
    if (w < 2) {
        unsigned short* outp = (w == 0) ? Q : K;
#pragma unroll
        for (int mt = 0; mt < 4; mt++)
#pragma unroll
            for (int nt = 0; nt < 4; nt++) {
                int row0 = m0 + wr * 64 + mt * 16 + g * 4;
                int col = wc * 64 + nt * 16 + l15;
#pragma unroll
                for (int ri = 0; ri < 4; ri++)
                    outp[(size_t)(row0 + ri) * H_ + col] = f2bf(acc[mt][nt][ri]);
            }
    } else {
        int b = m0 / T_;
        int tbase = m0 - b * T_;
#pragma unroll
        for (int mt = 0; mt < 4; mt++)
#pragma unroll
            for (int nt = 0; nt < 4; nt++) {
                int t0 = tbase + wr * 64 + mt * 16 + g * 4;
                int col = wc * 64 + nt * 16 + l15;
                u16x4 o;
                o.x = f2bf(acc[mt][nt][0]); o.y = f2bf(acc[mt][nt][1]);
                o.z = f2bf(acc[mt][nt][2]); o.w = f2bf(acc[mt][nt][3]);
                *(u16x4*)&Vt[(size_t)(b * H_ + col) * T_ + t0] = o;
            }
    }
}

// ---------------- Flash attention (split-K, no-max softmax) ----------------
// grid (T/64, 4, B). Block = (q-tile qb, K-segment seg, batch b).
// Segment covers k-tiles [seg*SEG_, min(qb, seg*SEG_+SEG_-1)].
// Writes UNNORMALIZED partial O (fp32) and partial l; combine_kernel sums.
__global__ __launch_bounds__(256) void attn_kernel(
        const unsigned short* __restrict__ Q, const unsigned short* __restrict__ K,
        const unsigned short* __restrict__ Vt,
        float* __restrict__ Opart, float* __restrict__ Lpart) {
    int qb = blockIdx.x, seg = blockIdx.y, b = blockIdx.z;
    if (seg * SEG_ > qb) return;
    __shared__ unsigned short Ks[64][136];   // +8 pad
    __shared__ unsigned short Vs[128][72];   // V^T tile [h][t], +8 pad
    __shared__ unsigned short Ps[4][16][72]; // per-wave P tile
    int tid = threadIdx.x, lane = tid & 63, wid = tid >> 6;
    int l15 = lane & 15, g = lane >> 4;
    int q0w = qb * 64 + wid * 16;
    const float alpha = 0.08838834764831845f; // 1/sqrt(128)

    short8 aq[4];
#pragma unroll
    for (int kf = 0; kf < 4; kf++)
        aq[kf] = *(const short8*)(Q + (size_t)(b * T_ + q0w + l15) * H_ + kf * 32 + g * 8);

    f32x4 o[8];
#pragma unroll
    for (int i = 0; i < 8; i++) o[i] = (f32x4)0.0f;
    float l_run[4];
#pragma unroll
    for (int ri = 0; ri < 4; ri++) l_run[ri] = 0.f;

    int kt_end = min(qb, seg * SEG_ + SEG_ - 1);
    for (int kt = seg * SEG_; kt <= kt_end; ++kt) {
        int k0 = kt * 64;
#pragma unroll
        for (int p = 0; p < 4; ++p) {
            int idx = tid + p * 256;
            int r = idx >> 4, c = (idx & 15) * 8;
            *(short8*)&Ks[r][c] = *(const short8*)(K + (size_t)(b * T_ + k0 + r) * H_ + c);
        }
#pragma unroll
        for (int p = 0; p < 4; ++p) {
            int idx = tid + p * 256;
            int r = idx >> 3, c = (idx & 7) * 8;
            *(short8*)&Vs[r][c] = *(const short8*)(Vt + (size_t)(b * H_ + r) * T_ + k0 + c);
        }
        __syncthreads();

        // S = Q K^T
        f32x4 s[4];
#pragma unroll
        for (int ct = 0; ct < 4; ct++) {
            s[ct] = (f32x4)0.0f;
#pragma unroll
            for (int kf = 0; kf < 4; kf++) {
                short8 bk = *(const short8*)&Ks[ct * 16 + l15][kf * 32 + g * 8];
                s[ct] = __builtin_amdgcn_mfma_f32_16x16x32_bf16(aq[kf], bk, s[ct], 0, 0, 0);
            }
        }
        bool diag = (kt == qb);
        // exp (no max subtraction), accumulate per-lane partial l, pack P
#pragma unroll
        for (int ct = 0; ct < 4; ct++)
#pragma unroll
            for (int ri = 0; ri < 4; ri++) {
                float v = s[ct][ri] * alpha;
                if (diag) {
                    int kkg = k0 + ct * 16 + l15;
                    int qg = q0w + g * 4 + ri;
                    if (kkg > qg) v = -1e30f;
                }
                float p = __expf(v);
                l_run[ri] += p;
                Ps[wid][g * 4 + ri][ct * 16 + l15] = f2bf(p);
            }

        // O += P V
#pragma unroll
        for (int kf2 = 0; kf2 < 2; kf2++) {
            short8 ap = *(const short8*)&Ps[wid][l15][kf2 * 32 + g * 8];
#pragma unroll
            for (int ht = 0; ht < 8; ht++) {
                short8 bv = *(const short8*)&Vs[ht * 16 + l15][kf2 * 32 + g * 8];
                o[ht] = __builtin_amdgcn_mfma_f32_16x16x32_bf16(ap, bv, o[ht], 0, 0, 0);
            }
        }
        __syncthreads();
    }

    // epilogue: reduce l across the 16 lanes of each row group, write partials
    int nslot = T_ / 64 / SEG_ * SEG_;  (void)nslot;
    size_t slot = (((size_t)b * (T_ / 64) + qb) * 4 + seg);
    float* Ob = Opart + slot * 64 * 128;
    float* Lb = Lpart + slot * 64;
#pragma unroll
    for (int ri = 0; ri < 4; ri++) {
        float l = l_run[ri];
#pragma unroll
        for (int off = 1; off < 16; off <<= 1)
            l += __shfl_xor(l, off, 64);
        int qrow = wid * 16 + g * 4 + ri;
        Lb[qrow] = l;
#pragma unroll
        for (int ht = 0; ht < 8; ht++)
            Ob[(size_t)qrow * 128 + ht * 16 + l15] = o[ht][ri];
    }
}

// ---------------- Combine: out = (sum_s Opart) / (sum_s Lpart) ----------------
__global__ __launch_bounds__(256) void combine_kernel(
        const float* __restrict__ Opart, const float* __restrict__ Lpart,
        float* __restrict__ out) {
    int qt = blockIdx.x, b = blockIdx.y;
    int nseg = qt / SEG_ + 1;
    int tid = threadIdx.x;
    size_t obase = (((size_t)b * (T_ / 64) + qt) * 4) * 64 * 128;
    size_t lbase = (((size_t)b * (T_ / 64) + qt) * 4) * 64;
    float4* dst = (float4*)(out + ((size_t)b * T_ + qt * 64) * 128);
#pragma unroll
    for (int i = 0; i < 8; ++i) {
        int e4 = tid + i * 256;       // float4 index within 64x128 tile
        int q = e4 >> 5;
        float4 acc = {0.f, 0.f, 0.f, 0.f};
        float lsum = 0.f;
        for (int s = 0; s < nseg; ++s) {
            float4 v = *((const float4*)(Opart + obase + (size_t)s * 64 * 128) + e4);
            acc.x += v.x; acc.y += v.y; acc.z += v.z; acc.w += v.w;
            lsum += Lpart[lbase + s * 64 + q];
        }
        float inv = 1.0f / lsum;
        float4 r = {acc.x * inv, acc.y * inv, acc.z * inv, acc.w * inv};
        dst[e4] = r;
    }
}

extern "C" void kernel_launch(void* const* d_in, const int* in_sizes, int n_in,
                              void* d_out, int out_size, void* d_ws, size_t ws_size,
                              hipStream_t stream) {
    const float* x  = (const float*)d_in[0];
    const float* Wq = (const float*)d_in[1];
    const float* Wk = (const float*)d_in[2];
    const float* Wv = (const float*)d_in[3];
    float* out = (float*)d_out;

    unsigned short* Wt = (unsigned short*)d_ws;              // [3][H][C] bf16
    unsigned short* Qb = Wt + 3 * (size_t)H_ * C_;           // [B][T][H] bf16
    unsigned short* Kb = Qb + (size_t)B_ * T_ * H_;          // [B][T][H] bf16
    unsigned short* Vt = Kb + (size_t)B_ * T_ * H_;          // [B][H][T] bf16
    float* Opart = (float*)(Vt + (size_t)B_ * T_ * H_);      // [B][64][4][64][128] f32 (32MB)
    float* Lpart = Opart + (size_t)B_ * 64 * 4 * 64 * 128;   // [B][64][4][64] f32

    wt_kernel<<<dim3(C_ / 64, H_ / 64, 3), 256, 0, stream>>>(Wq, Wk, Wv, Wt);
    proj_kernel<<<dim3((B_ * T_) / 128, 3), 256, 0, stream>>>(x, Wt, Qb, Kb, Vt);
    attn_kernel<<<dim3(T_ / 64, 4, B_), 256, 0, stream>>>(Qb, Kb, Vt, Opart, Lpart);
    combine_kernel<<<dim3(T_ / 64, B_), 256, 0, stream>>>(Opart, Lpart, out);
}

// Round 4
// 199.168 us; speedup vs baseline: 1.3049x; 1.0337x over previous
//
#include <hip/hip_runtime.h>
#include <hip/hip_bf16.h>

#define B_ 4
#define T_ 4096
#define C_ 1024
#define H_ 128
#define SEG_ 16   // K-tiles per segment (16*64=1024 keys)

typedef __attribute__((ext_vector_type(8))) short short8;
typedef __attribute__((ext_vector_type(4))) float f32x4;
typedef __attribute__((ext_vector_type(4))) unsigned short u16x4;

static __device__ __forceinline__ unsigned short f2bf(float f) {
    union { float f; unsigned u; } v; v.f = f;
    unsigned r = v.u + 0x7FFF + ((v.u >> 16) & 1);
    return (unsigned short)(r >> 16);
}

// ---------------- x fp32 -> bf16 (streaming) ----------------
__global__ __launch_bounds__(256) void xb_kernel(const float* __restrict__ x,
                                                 unsigned short* __restrict__ xb) {
#pragma unroll
    for (int p = 0; p < 8; ++p) {
        size_t e = (size_t)blockIdx.x * 2048 + p * 256 + threadIdx.x; // float4 units
        float4 v = ((const float4*)x)[e];
        u16x4 o;
        o.x = f2bf(v.x); o.y = f2bf(v.y); o.z = f2bf(v.z); o.w = f2bf(v.w);
        ((u16x4*)xb)[e] = o;
    }
}

// ---------------- W transpose: [C][H] fp32 -> [H][C] bf16 ----------------
__global__ void wt_kernel(const float* __restrict__ Wq, const float* __restrict__ Wk,
                          const float* __restrict__ Wv, unsigned short* __restrict__ Wt) {
    __shared__ float tile[64][65];
    int c0 = blockIdx.x * 64, h0 = blockIdx.y * 64, w = blockIdx.z;
    const float* W = (w == 0) ? Wq : (w == 1) ? Wk : Wv;
    unsigned short* dst = Wt + (size_t)w * H_ * C_;
    int tr = threadIdx.x >> 6, tc = threadIdx.x & 63;
#pragma unroll
    for (int p = 0; p < 16; ++p) {
        int r = p * 4 + tr;
        tile[r][tc] = W[(size_t)(c0 + r) * H_ + h0 + tc];
    }
    __syncthreads();
#pragma unroll
    for (int p = 0; p < 16; ++p) {
        int r = p * 4 + tr; // h index
        dst[(size_t)(h0 + r) * C_ + c0 + tc] = f2bf(tile[tc][r]);
    }
}

// ---------------- QKV projection GEMM: [16384 x 1024](bf16) * [1024 x 128] ----------------
// grid (M/128, 3). w=0 -> Q row-major, w=1 -> K row-major, w=2 -> V transposed [B][H][T]
// LDS tiles [128][64] bf16, XOR-swizzled: granule' = granule ^ (row&7)
__global__ __launch_bounds__(256) void proj_kernel(
        const unsigned short* __restrict__ xb, const unsigned short* __restrict__ Wt3,
        unsigned short* __restrict__ Q, unsigned short* __restrict__ K,
        unsigned short* __restrict__ Vt) {
    __shared__ unsigned short Xs[128 * 64];
    __shared__ unsigned short Ws[128 * 64];
    int m0 = blockIdx.x * 128;
    int w = blockIdx.y;
    const unsigned short* Wt = Wt3 + (size_t)w * H_ * C_;
    int tid = threadIdx.x;
    int lane = tid & 63, wid = tid >> 6;
    int wr = wid >> 1, wc = wid & 1;
    int l15 = lane & 15, g = lane >> 4;
    int l7 = l15 & 7;

    f32x4 acc[4][4];
#pragma unroll
    for (int i = 0; i < 4; i++)
#pragma unroll
        for (int j = 0; j < 4; j++) acc[i][j] = (f32x4)0.0f;

    for (int kt = 0; kt < C_ / 64; ++kt) {
        int k0 = kt * 64;
#pragma unroll
        for (int p = 0; p < 4; ++p) {
            int idx = tid + p * 256;
            int r = idx >> 3, c = idx & 7;
            short8 v = *(const short8*)(xb + (size_t)(m0 + r) * C_ + k0 + c * 8);
            *(short8*)&Xs[r * 64 + ((c ^ (r & 7)) << 3)] = v;
        }
#pragma unroll
        for (int p = 0; p < 4; ++p) {
            int idx = tid + p * 256;
            int r = idx >> 3, c = idx & 7;
            short8 v = *(const short8*)(Wt + (size_t)r * C_ + k0 + c * 8);
            *(short8*)&Ws[r * 64 + ((c ^ (r & 7)) << 3)] = v;
        }
        __syncthreads();
#pragma unroll
        for (int kf = 0; kf < 2; ++kf) {
            short8 a[4], bvec[4];
#pragma unroll
            for (int mt = 0; mt < 4; mt++) {
                int row = wr * 64 + mt * 16 + l15;
                a[mt] = *(const short8*)&Xs[row * 64 + (((kf * 4 + g) ^ l7) << 3)];
            }
#pragma unroll
            for (int nt = 0; nt < 4; nt++) {
                int row = wc * 64 + nt * 16 + l15;
                bvec[nt] = *(const short8*)&Ws[row * 64 + (((kf * 4 + g) ^ l7) << 3)];
            }
#pragma unroll
            for (int mt = 0; mt < 4; mt++)
#pragma unroll
                for (int nt = 0; nt < 4; nt++)
                    acc[mt][nt] = __builtin_amdgcn_mfma_f32_16x16x32_bf16(a[mt], bvec[nt], acc[mt][nt], 0, 0, 0);
        }
        __syncthreads();
    }
    if (w < 2) {
        unsigned short* outp = (w == 0) ? Q : K;
#pragma unroll
        for (int mt = 0; mt < 4; mt++)
#pragma unroll
            for (int nt = 0; nt < 4; nt++) {
                int row0 = m0 + wr * 64 + mt * 16 + g * 4;
                int col = wc * 64 + nt * 16 + l15;
#pragma unroll
                for (int ri = 0; ri < 4; ri++)
                    outp[(size_t)(row0 + ri) * H_ + col] = f2bf(acc[mt][nt][ri]);
            }
    } else {
        int b = m0 / T_;
        int tbase = m0 - b * T_;
#pragma unroll
        for (int mt = 0; mt < 4; mt++)
#pragma unroll
            for (int nt = 0; nt < 4; nt++) {
                int t0 = tbase + wr * 64 + mt * 16 + g * 4;
                int col = wc * 64 + nt * 16 + l15;
                u16x4 o;
                o.x = f2bf(acc[mt][nt][0]); o.y = f2bf(acc[mt][nt][1]);
                o.z = f2bf(acc[mt][nt][2]); o.w = f2bf(acc[mt][nt][3]);
                *(u16x4*)&Vt[(size_t)(b * H_ + col) * T_ + t0] = o;
            }
    }
}

// ---------------- Flash attention (split-K, no-max softmax, swizzled LDS, K/V prefetch) ----------------
// grid (T/64, 4, B). Segment covers k-tiles [seg*SEG_, min(qb, seg*SEG_+SEG_-1)].
__global__ __launch_bounds__(256) void attn_kernel(
        const unsigned short* __restrict__ Q, const unsigned short* __restrict__ K,
        const unsigned short* __restrict__ Vt,
        float* __restrict__ Opart, float* __restrict__ Lpart) {
    int qb = blockIdx.x, seg = blockIdx.y, b = blockIdx.z;
    if (seg * SEG_ > qb) return;
    __shared__ unsigned short KsF[64 * 128];   // XOR-swizzled
    __shared__ unsigned short VsF[128 * 64];   // V^T tile [h][t], XOR-swizzled
    __shared__ unsigned short PsF[4][16 * 64]; // per-wave P tile, XOR-swizzled
    int tid = threadIdx.x, lane = tid & 63, wid = tid >> 6;
    int l15 = lane & 15, g = lane >> 4;
    int l7 = l15 & 7;
    int q0w = qb * 64 + wid * 16;
    const float alpha = 0.08838834764831845f; // 1/sqrt(128)

    short8 aq[4];
#pragma unroll
    for (int kf = 0; kf < 4; kf++)
        aq[kf] = *(const short8*)(Q + (size_t)(b * T_ + q0w + l15) * H_ + kf * 32 + g * 8);

    f32x4 o[8];
#pragma unroll
    for (int i = 0; i < 8; i++) o[i] = (f32x4)0.0f;
    float l_run[4];
#pragma unroll
    for (int ri = 0; ri < 4; ri++) l_run[ri] = 0.f;

    int kt0 = seg * SEG_;
    int kt_end = min(qb, kt0 + SEG_ - 1);

    short8 kreg[4], vreg[4];
#define LOAD_KV(KT) do { int k0_ = (KT) * 64; \
    _Pragma("unroll") \
    for (int p = 0; p < 4; ++p) { int idx = tid + p * 256; \
        kreg[p] = *(const short8*)(K + (size_t)(b * T_ + k0_ + (idx >> 4)) * H_ + (idx & 15) * 8); } \
    _Pragma("unroll") \
    for (int p = 0; p < 4; ++p) { int idx = tid + p * 256; \
        vreg[p] = *(const short8*)(Vt + (size_t)(b * H_ + (idx >> 3)) * T_ + k0_ + (idx & 7) * 8); } \
    } while (0)

    LOAD_KV(kt0);
    for (int kt = kt0; kt <= kt_end; ++kt) {
        int k0 = kt * 64;
        __syncthreads();   // previous iter's LDS reads complete
#pragma unroll
        for (int p = 0; p < 4; ++p) {
            int idx = tid + p * 256;
            int r = idx >> 4;
            *(short8*)&KsF[r * 128 + (((idx & 15) ^ (r & 7)) << 3)] = kreg[p];
        }
#pragma unroll
        for (int p = 0; p < 4; ++p) {
            int idx = tid + p * 256;
            int r = idx >> 3;
            *(short8*)&VsF[r * 64 + (((idx & 7) ^ (r & 7)) << 3)] = vreg[p];
        }
        __syncthreads();   // tiles visible
        if (kt < kt_end) LOAD_KV(kt + 1);  // prefetch overlaps compute

        // S = Q K^T
        f32x4 s[4];
#pragma unroll
        for (int ct = 0; ct < 4; ct++) {
            s[ct] = (f32x4)0.0f;
#pragma unroll
            for (int kf = 0; kf < 4; kf++) {
                int row = ct * 16 + l15;
                short8 bk = *(const short8*)&KsF[row * 128 + (((kf * 4 + g) ^ l7) << 3)];
                s[ct] = __builtin_amdgcn_mfma_f32_16x16x32_bf16(aq[kf], bk, s[ct], 0, 0, 0);
            }
        }
        bool diag = (kt == qb);
        // exp (no max subtraction), accumulate per-lane partial l, pack P (swizzled)
#pragma unroll
        for (int ct = 0; ct < 4; ct++)
#pragma unroll
            for (int ri = 0; ri < 4; ri++) {
                float v = s[ct][ri] * alpha;
                if (diag) {
                    int kkg = k0 + ct * 16 + l15;
                    int qg = q0w + g * 4 + ri;
                    if (kkg > qg) v = -1e30f;
                }
                float p = __expf(v);
                l_run[ri] += p;
                int row = g * 4 + ri;
                PsF[wid][row * 64 + (((2 * ct + (l15 >> 3)) ^ (row & 7)) << 3) + l7] = f2bf(p);
            }

        // O += P V
#pragma unroll
        for (int kf2 = 0; kf2 < 2; kf2++) {
            short8 ap = *(const short8*)&PsF[wid][l15 * 64 + (((kf2 * 4 + g) ^ l7) << 3)];
#pragma unroll
            for (int ht = 0; ht < 8; ht++) {
                int row = ht * 16 + l15;
                short8 bv = *(const short8*)&VsF[row * 64 + (((kf2 * 4 + g) ^ l7) << 3)];
                o[ht] = __builtin_amdgcn_mfma_f32_16x16x32_bf16(ap, bv, o[ht], 0, 0, 0);
            }
        }
    }
#undef LOAD_KV

    // epilogue: reduce l across the 16 lanes of each row group, write partials
    size_t slot = (((size_t)b * (T_ / 64) + qb) * 4 + seg);
    float* Ob = Opart + slot * 64 * 128;
    float* Lb = Lpart + slot * 64;
#pragma unroll
    for (int ri = 0; ri < 4; ri++) {
        float l = l_run[ri];
#pragma unroll
        for (int off = 1; off < 16; off <<= 1)
            l += __shfl_xor(l, off, 64);
        int qrow = wid * 16 + g * 4 + ri;
        Lb[qrow] = l;
#pragma unroll
        for (int ht = 0; ht < 8; ht++)
            Ob[(size_t)qrow * 128 + ht * 16 + l15] = o[ht][ri];
    }
}

// ---------------- Combine: out = (sum_s Opart) / (sum_s Lpart) ----------------
__global__ __launch_bounds__(256) void combine_kernel(
        const float* __restrict__ Opart, const float* __restrict__ Lpart,
        float* __restrict__ out) {
    int qt = blockIdx.x, b = blockIdx.y;
    int nseg = qt / SEG_ + 1;
    int tid = threadIdx.x;
    size_t obase = (((size_t)b * (T_ / 64) + qt) * 4) * 64 * 128;
    size_t lbase = (((size_t)b * (T_ / 64) + qt) * 4) * 64;
    float4* dst = (float4*)(out + ((size_t)b * T_ + qt * 64) * 128);
#pragma unroll
    for (int i = 0; i < 8; ++i) {
        int e4 = tid + i * 256;       // float4 index within 64x128 tile
        int q = e4 >> 5;
        float4 acc = {0.f, 0.f, 0.f, 0.f};
        float lsum = 0.f;
        for (int s = 0; s < nseg; ++s) {
            float4 v = *((const float4*)(Opart + obase + (size_t)s * 64 * 128) + e4);
            acc.x += v.x; acc.y += v.y; acc.z += v.z; acc.w += v.w;
            lsum += Lpart[lbase + s * 64 + q];
        }
        float inv = 1.0f / lsum;
        float4 r = {acc.x * inv, acc.y * inv, acc.z * inv, acc.w * inv};
        dst[e4] = r;
    }
}

extern "C" void kernel_launch(void* const* d_in, const int* in_sizes, int n_in,
                              void* d_out, int out_size, void* d_ws, size_t ws_size,
                              hipStream_t stream) {
    const float* x  = (const float*)d_in[0];
    const float* Wq = (const float*)d_in[1];
    const float* Wk = (const float*)d_in[2];
    const float* Wv = (const float*)d_in[3];
    float* out = (float*)d_out;

    unsigned short* Wt = (unsigned short*)d_ws;              // [3][H][C] bf16   (768KB)
    unsigned short* xbp = Wt + 3 * (size_t)H_ * C_;          // [B*T][C] bf16    (33.5MB)
    unsigned short* Qb = xbp + (size_t)B_ * T_ * C_;         // [B][T][H] bf16
    unsigned short* Kb = Qb + (size_t)B_ * T_ * H_;          // [B][T][H] bf16
    unsigned short* Vt = Kb + (size_t)B_ * T_ * H_;          // [B][H][T] bf16
    float* Opart = (float*)(Vt + (size_t)B_ * T_ * H_);      // [B][64][4][64][128] f32 (33.5MB)
    float* Lpart = Opart + (size_t)B_ * 64 * 4 * 64 * 128;   // [B][64][4][64] f32

    xb_kernel<<<dim3((B_ * T_ * C_ / 4) / 2048), 256, 0, stream>>>(x, xbp);
    wt_kernel<<<dim3(C_ / 64, H_ / 64, 3), 256, 0, stream>>>(Wq, Wk, Wv, Wt);
    proj_kernel<<<dim3((B_ * T_) / 128, 3), 256, 0, stream>>>(xbp, Wt, Qb, Kb, Vt);
    attn_kernel<<<dim3(T_ / 64, 4, B_), 256, 0, stream>>>(Qb, Kb, Vt, Opart, Lpart);
    combine_kernel<<<dim3(T_ / 64, B_), 256, 0, stream>>>(Opart, Lpart, out);
}